// Round 6
// baseline (3309.163 us; speedup 1.0000x reference)
//
#include <hip/hip_runtime.h>
#include <math.h>

#define B_ 64
#define T_ 32
#define N_ 12
#define NS_ 132
#define KN_ 11
#define TEMP_ 1.375f   // K_NEIGH / sqrt(ATTN) = 11/8

typedef unsigned short u16;
typedef __attribute__((ext_vector_type(8))) short bf16x8;
typedef __attribute__((ext_vector_type(8))) unsigned short u16x8;
typedef __attribute__((ext_vector_type(4))) float f32x4;

__device__ __forceinline__ float sigm(float x) { return 1.f / (1.f + __expf(-x)); }
__device__ __forceinline__ float ftanh(float x) {
    float a = fabsf(x);
    float e = __expf(-2.f * a);
    float t = (1.f - e) / (1.f + e);
    return copysignf(t, x);
}
__device__ __forceinline__ u16 f2bf(float x) {
    union { float f; unsigned u; } v; v.f = x;
    unsigned r = v.u + 0x7fffu + ((v.u >> 16) & 1u);
    return (u16)(r >> 16);
}
__device__ __forceinline__ float bf2f(u16 h) {
    union { unsigned u; float f; } v; v.u = ((unsigned)h) << 16; return v.f;
}
// reordered gate-space col j -> original gate col: j = cellhi*64 + gate*16 + celllo
__device__ __forceinline__ int origcol(int j) {
    return ((j >> 4) & 3) * 256 + ((j >> 6) << 4) + (j & 15);
}

// Fragment layout for M[R][K] (A/B operand of mfma 16x16x32 bf16):
//   tile = (r>>4)*(K/32) + (k>>5); lane = ((k>>3)&3)*16 + (r&15); elem = k&7
//   flat u16 index = tile*512 + lane*8 + elem

// ---------------------------------------------------------------------------
// prep: all weights -> bf16 fragment layout, fused biases.
// ---------------------------------------------------------------------------
__global__ __launch_bounds__(256) void prep_kernel(
    const float* __restrict__ te_Wih, const float* __restrict__ te_Whh,
    const float* __restrict__ te_bih, const float* __restrict__ te_bhh,
    const float* __restrict__ se_Wih, const float* __restrict__ se_Whh,
    const float* __restrict__ se_bih, const float* __restrict__ se_bhh,
    const float* __restrict__ nr_Wih, const float* __restrict__ nr_Whh,
    const float* __restrict__ nr_bih, const float* __restrict__ nr_bhh,
    const float* __restrict__ Wq, const float* __restrict__ Wk,
    const float* __restrict__ W_edge,
    u16* __restrict__ Wf_t, u16* __restrict__ Wf_s, u16* __restrict__ Wf_n,
    float* __restrict__ bs_t, float* __restrict__ bs_s, float* __restrict__ bs_n,
    u16* __restrict__ Wqf, u16* __restrict__ Wkqf, u16* __restrict__ Wef)
{
    int idx = blockIdx.x * 256 + threadIdx.x;
    if (idx < 49152) {                 // Wf_t / Wf_s: 64 jb16 x 12 kc x 64 lanes
        int l = idx & 63, kc = (idx >> 6) % 12, jb16 = idx / 768;
        int j = jb16 * 16 + (l & 15);
        int c = origcol(j);
        int k0 = kc * 32 + (l >> 4) * 8;
        u16x8 vt, vs;
        #pragma unroll
        for (int i = 0; i < 8; ++i) {
            int k = k0 + i;
            vt[i] = f2bf((k < 128) ? te_Wih[c * 128 + k] : te_Whh[c * 256 + (k - 128)]);
            vs[i] = f2bf((k < 128) ? se_Wih[c * 128 + k] : se_Whh[c * 256 + (k - 128)]);
        }
        *(u16x8*)(Wf_t + (size_t)idx * 8) = vt;
        *(u16x8*)(Wf_s + (size_t)idx * 8) = vs;
    }
    if (idx < 65536) {                 // Wf_n: 64 jb16 x 16 kc x 64 lanes
        int l = idx & 63, kc = (idx >> 6) & 15, jb16 = idx >> 10;
        int j = jb16 * 16 + (l & 15);
        int c = origcol(j);
        int k0 = kc * 32 + (l >> 4) * 8;
        u16x8 vn;
        #pragma unroll
        for (int i = 0; i < 8; ++i) {
            int k = k0 + i;
            vn[i] = f2bf((k < 256) ? nr_Wih[c * 256 + k] : nr_Whh[c * 256 + (k - 256)]);
        }
        *(u16x8*)(Wf_n + (size_t)idx * 8) = vn;
    }
    if (idx < 1024) {
        int c = origcol(idx);
        bs_t[idx] = te_bih[c] + te_bhh[c];
        bs_s[idx] = se_bih[c] + se_bhh[c];
        bs_n[idx] = nr_bih[c] + nr_bhh[c];
    }
    if (idx < 2048) {                  // Wqf: B[a][k], a<64, K=256 -> 4 jb x 8 kc
        int l = idx & 63, tile = idx >> 6;
        int a = (tile >> 3) * 16 + (l & 15);
        int k0 = (tile & 7) * 32 + (l >> 4) * 8;
        u16x8 v;
        #pragma unroll
        for (int i = 0; i < 8; ++i) v[i] = f2bf(Wq[a * 256 + k0 + i]);
        *(u16x8*)(Wqf + (size_t)idx * 8) = v;
    }
    if (idx < 2048) {                  // Wkqf: B[j][a] = Wk[a][j], j<256, K=64 -> 16 jb x 2 kc
        int l = idx & 63, tile = idx >> 6;
        int j = (tile >> 1) * 16 + (l & 15);
        int a0 = (tile & 1) * 32 + (l >> 4) * 8;
        u16x8 v;
        #pragma unroll
        for (int i = 0; i < 8; ++i) v[i] = f2bf(Wk[(a0 + i) * 256 + j]);
        *(u16x8*)(Wkqf + (size_t)idx * 8) = v;
    }
    if (idx < 8192) {                  // Wef: B[c][k], c<128, K=512 -> 8 jb x 16 kc
        int l = idx & 63, tile = idx >> 6;
        int c = (tile >> 4) * 16 + (l & 15);
        int k0 = (tile & 15) * 32 + (l >> 4) * 8;
        u16x8 v;
        #pragma unroll
        for (int i = 0; i < 8; ++i) v[i] = f2bf(W_edge[c * 512 + k0 + i]);
        *(u16x8*)(Wef + (size_t)idx * 8) = v;
    }
}

// te/nin embeddings in fragment layout: u = ((t*48+rb16)*4+kc)*64 + l
__global__ __launch_bounds__(256) void emb_tn_kernel(
    const float* __restrict__ et, const float* __restrict__ nodes,
    const float* __restrict__ W_te, const float* __restrict__ b_te,
    const float* __restrict__ W_node, const float* __restrict__ b_node,
    u16* __restrict__ tef, u16* __restrict__ ninf)
{
    int u = blockIdx.x * 256 + threadIdx.x;   // 32*48*4*64 = 393216 exact
    int l = u & 63, kc = (u >> 6) & 3;
    int rt = u >> 8;
    int rb16 = rt % 48, t = rt / 48;
    int row = rb16 * 16 + (l & 15);
    int b = row / 12, n = row - b * 12;
    size_t src = (((size_t)b * T_ + t) * N_ + n) * 2;
    float e0 = et[src], e1 = et[src + 1];
    float n0 = nodes[src], n1 = nodes[src + 1];
    int k0 = kc * 32 + (l >> 4) * 8;
    u16x8 vt, vn;
    #pragma unroll
    for (int i = 0; i < 8; ++i) {
        int k = k0 + i;
        float x = fmaf(e0, W_te[k * 2], fmaf(e1, W_te[k * 2 + 1], b_te[k]));
        vt[i] = f2bf(fmaxf(x, 0.f));
        float y = fmaf(n0, W_node[k * 2], fmaf(n1, W_node[k * 2 + 1], b_node[k]));
        vn[i] = f2bf(fmaxf(y, 0.f));
    }
    *(u16x8*)(tef + (size_t)u * 8) = vt;
    *(u16x8*)(ninf + (size_t)u * 8) = vn;
}

// spatial embeddings, fragment layout: u = ((trel*528+rb16)*4+kc)*64 + l
__global__ __launch_bounds__(256) void emb_se_kernel(
    int t0, const float* __restrict__ es,
    const float* __restrict__ W_se, const float* __restrict__ b_se,
    u16* __restrict__ sef)
{
    int u = blockIdx.x * 256 + threadIdx.x;
    int l = u & 63, kc = (u >> 6) & 3;
    int rt = u >> 8;
    int rb16 = rt % 528, trel = rt / 528;
    int row = rb16 * 16 + (l & 15);
    int b = row / NS_, s = row - b * NS_;
    size_t src = (((size_t)b * T_ + (t0 + trel)) * NS_ + s) * 2;
    float e0 = es[src], e1 = es[src + 1];
    int k0 = kc * 32 + (l >> 4) * 8;
    u16x8 v;
    #pragma unroll
    for (int i = 0; i < 8; ++i) {
        int k = k0 + i;
        float x = fmaf(e0, W_se[k * 2], fmaf(e1, W_se[k * 2 + 1], b_se[k]));
        v[i] = f2bf(fmaxf(x, 0.f));
    }
    *(u16x8*)(sef + (size_t)u * 8) = v;
}

// ---------------------------------------------------------------------------
// step_kernel: blocks [0, nlstm) = temporal+spatial LSTM step t+1;
// blocks [nlstm, nlstm+48) = attention + edge-input + node LSTM for step t
// (fully self-contained per 16-row block; ein lives in LDS fragments).
// ---------------------------------------------------------------------------
__global__ __launch_bounds__(256) void step_kernel(
    int nlstm, int t_node,
    const u16* __restrict__ sef_step, const u16* __restrict__ tef_step,
    const u16* __restrict__ Wf_t, const float* __restrict__ bs_t,
    const u16* __restrict__ Wf_s, const float* __restrict__ bs_s,
    const u16* __restrict__ htf_p, u16* __restrict__ htf_c, float* __restrict__ c_t,
    const u16* __restrict__ hsf_p, u16* __restrict__ hsf_c,
    u16* __restrict__ hsd_w, float* __restrict__ c_s,
    const u16* __restrict__ hsd_r,
    const u16* __restrict__ ninf_t,
    const u16* __restrict__ Wf_n, const float* __restrict__ bs_n,
    const u16* __restrict__ hnf_p, u16* __restrict__ hnf_c,
    u16* __restrict__ hist1, float* __restrict__ c_n,
    const u16* __restrict__ Wqf, const float* __restrict__ bq,
    const u16* __restrict__ Wkqf, const float* __restrict__ bk,
    const u16* __restrict__ Wef, const float* __restrict__ b_edge)
{
    const int tid = threadIdx.x;
    const int l = tid & 63, l15 = l & 15;
    const size_t lo8 = (size_t)l * 8;

    if ((int)blockIdx.x < nlstm) {
        // ================= temporal+spatial LSTM tile =================
        const bool spatial = blockIdx.x < 528;
        int rb, jc;
        if (spatial) {
            int orig = (blockIdx.x & 7) * 66 + (blockIdx.x >> 3);   // XCD chunking
            rb = orig >> 3; jc = orig & 7;
        } else {
            int q = blockIdx.x - 528;
            rb = q >> 3; jc = q & 7;
        }
        const u16* Ef = spatial ? sef_step : tef_step;
        const u16* Hf = spatial ? hsf_p : htf_p;
        const u16* Wf = spatial ? Wf_s : Wf_t;
        const float* bs = spatial ? bs_s : bs_t;
        u16* Hfc = spatial ? hsf_c : htf_c;
        float* C  = spatial ? c_s : c_t;

        const int wid = tid >> 6;
        const int wm = wid >> 1, wn = wid & 1;
        const int rb16 = rb * 8 + wm * 4;
        const int jb16 = jc * 8 + wn * 4;

        f32x4 acc[4][4];
        #pragma unroll
        for (int g = 0; g < 4; ++g) {
            float bv = bs[jc * 128 + wn * 64 + g * 16 + l15];
            #pragma unroll
            for (int mf = 0; mf < 4; ++mf) acc[mf][g] = (f32x4){bv, bv, bv, bv};
        }

        auto loadA = [&](int kc, bf16x8* a) {
            #pragma unroll
            for (int mf = 0; mf < 4; ++mf) {
                const u16* p = (kc < 4)
                    ? Ef + (((size_t)(rb16 + mf)) * 4 + kc) * 512 + lo8
                    : Hf + (((size_t)(rb16 + mf)) * 8 + (kc - 4)) * 512 + lo8;
                a[mf] = *(const bf16x8*)p;
            }
        };
        auto loadB = [&](int kc, bf16x8* b) {
            #pragma unroll
            for (int g = 0; g < 4; ++g)
                b[g] = *(const bf16x8*)(Wf + (((size_t)(jb16 + g)) * 12 + kc) * 512 + lo8);
        };
        auto domfma = [&](bf16x8* a, bf16x8* b) {
            #pragma unroll
            for (int mf = 0; mf < 4; ++mf)
                #pragma unroll
                for (int g = 0; g < 4; ++g)
                    acc[mf][g] = __builtin_amdgcn_mfma_f32_16x16x32_bf16(a[mf], b[g], acc[mf][g], 0, 0, 0);
        };

        bf16x8 a0[4], b0[4], a1[4], b1[4];
        loadA(0, a0); loadB(0, b0);
        #pragma unroll
        for (int kc = 0; kc < 12; kc += 2) {
            loadA(kc + 1, a1); loadB(kc + 1, b1);
            domfma(a0, b0);
            if (kc + 2 < 12) { loadA(kc + 2, a0); loadB(kc + 2, b0); }
            domfma(a1, b1);
        }

        const int cell = (jc * 2 + wn) * 16 + l15;
        const int rofs = (l >> 4) << 2;
        const int cpart = (cell >> 5) * 512 + ((cell >> 3) & 3) * 128 + (cell & 7);
        #pragma unroll
        for (int mf = 0; mf < 4; ++mf) {
            int r16 = rb16 + mf;
            #pragma unroll
            for (int r = 0; r < 4; ++r) {
                int rlow = rofs + r;
                size_t doff = ((size_t)r16 * 16 + rlow) * 256 + cell;
                float gi = acc[mf][0][r], gf = acc[mf][1][r], gg = acc[mf][2][r], go = acc[mf][3][r];
                float c2 = sigm(gf) * C[doff] + sigm(gi) * ftanh(gg);
                float h2 = sigm(go) * ftanh(c2);
                C[doff] = c2;
                u16 hb = f2bf(h2);
                if (spatial) hsd_w[doff] = hb;
                Hfc[(size_t)r16 * 4096 + cpart + rlow * 8] = hb;
            }
        }
        return;
    }

    // ================= attn + edge + node LSTM (step t_node) =================
    if (t_node < 0) return;
    const int rb16n = blockIdx.x - nlstm;   // 0..47
    const int wid = tid >> 6;

    __shared__ float q_lds[16][68];
    __shared__ float shbuf[16][260];        // qk, then (after 2 barriers) h_attn
    __shared__ float sc_lds[16][12];
    __shared__ float w_lds[16][12];
    __shared__ float qb_lds[16];
    __shared__ u16 einL[2048];              // ein fragments: 4 tiles x 512

    if (wid == 0) {   // q = h_t @ Wq^T : 4 jb x 8 kc
        f32x4 qa[4];
        #pragma unroll
        for (int jb = 0; jb < 4; ++jb) qa[jb] = (f32x4){0.f, 0.f, 0.f, 0.f};
        #pragma unroll
        for (int kc = 0; kc < 8; ++kc) {
            bf16x8 af = *(const bf16x8*)(htf_p + ((size_t)rb16n * 8 + kc) * 512 + lo8);
            #pragma unroll
            for (int jb = 0; jb < 4; ++jb) {
                bf16x8 bf = *(const bf16x8*)(Wqf + ((size_t)(jb * 8 + kc)) * 512 + lo8);
                qa[jb] = __builtin_amdgcn_mfma_f32_16x16x32_bf16(af, bf, qa[jb], 0, 0, 0);
            }
        }
        #pragma unroll
        for (int jb = 0; jb < 4; ++jb) {
            int a = jb * 16 + l15;
            #pragma unroll
            for (int r = 0; r < 4; ++r)
                q_lds[(l >> 4) * 4 + r][a] = qa[jb][r] + bq[a];
        }
    }
    __syncthreads();
    if (wid == 0) {   // qk = q @ Wk : 2 halves x 8 jb x 2 kc (K = 64)
        #pragma unroll
        for (int half = 0; half < 2; ++half) {
            f32x4 ka[8];
            #pragma unroll
            for (int jb = 0; jb < 8; ++jb) ka[jb] = (f32x4){0.f, 0.f, 0.f, 0.f};
            #pragma unroll
            for (int kc = 0; kc < 2; ++kc) {
                int a0 = kc * 32 + (l >> 4) * 8;
                bf16x8 af;
                #pragma unroll
                for (int e = 0; e < 8; ++e)
                    ((u16*)&af)[e] = f2bf(q_lds[l15][a0 + e]);
                #pragma unroll
                for (int jb = 0; jb < 8; ++jb) {
                    bf16x8 bf = *(const bf16x8*)(Wkqf + ((size_t)((half * 8 + jb) * 2 + kc)) * 512 + lo8);
                    ka[jb] = __builtin_amdgcn_mfma_f32_16x16x32_bf16(af, bf, ka[jb], 0, 0, 0);
                }
            }
            #pragma unroll
            for (int jb = 0; jb < 8; ++jb)
                #pragma unroll
                for (int r = 0; r < 4; ++r)
                    shbuf[(l >> 4) * 4 + r][(half * 8 + jb) * 16 + l15] = ka[jb][r];
        }
    }
    if (wid == 1 && l < 16) {   // qb[row] = q_full . bk
        float s = 0.f;
        for (int a = 0; a < 64; ++a) s = fmaf(q_lds[l][a], bk[a], s);
        qb_lds[l] = s;
    }
    __syncthreads();
    if (tid < 176) {   // scores: (row, kk), qk in shbuf
        int row = tid / 11, kk = tid - row * 11;
        int r = rb16n * 16 + row;
        int srow = (r / 12) * 132 + (r % 12) * 11 + kk;
        const u16* hp = hsd_r + (size_t)srow * 256;
        float s = 0.f;
        for (int k = 0; k < 256; k += 8) {
            u16x8 v = *(const u16x8*)(hp + k);
            #pragma unroll
            for (int e = 0; e < 8; ++e) s = fmaf(shbuf[row][k + e], bf2f(v[e]), s);
        }
        sc_lds[row][kk] = (s + qb_lds[row]) * TEMP_;
    }
    __syncthreads();
    if (tid < 16) {   // softmax over 11
        float m = sc_lds[tid][0];
        #pragma unroll
        for (int kk = 1; kk < 11; ++kk) m = fmaxf(m, sc_lds[tid][kk]);
        float ssum = 0.f;
        float wv[11];
        #pragma unroll
        for (int kk = 0; kk < 11; ++kk) { wv[kk] = __expf(sc_lds[tid][kk] - m); ssum += wv[kk]; }
        float inv = 1.f / ssum;
        #pragma unroll
        for (int kk = 0; kk < 11; ++kk) w_lds[tid][kk] = wv[kk] * inv;
    }
    __syncthreads();
    {   // h_attn -> shbuf (qk dead now): thread = (row, 16-col chunk)
        int row = tid >> 4, c0 = (tid & 15) * 16;
        int r = rb16n * 16 + row;
        int sbase = (r / 12) * 132 + (r % 12) * 11;
        float hacc[16];
        #pragma unroll
        for (int e = 0; e < 16; ++e) hacc[e] = 0.f;
        #pragma unroll
        for (int kk = 0; kk < 11; ++kk) {
            float wv = w_lds[row][kk];
            const u16* hp = hsd_r + (size_t)(sbase + kk) * 256 + c0;
            u16x8 v0 = *(const u16x8*)hp;
            u16x8 v1 = *(const u16x8*)(hp + 8);
            #pragma unroll
            for (int e = 0; e < 8; ++e) {
                hacc[e]     = fmaf(wv, bf2f(v0[e]), hacc[e]);
                hacc[8 + e] = fmaf(wv, bf2f(v1[e]), hacc[8 + e]);
            }
        }
        #pragma unroll
        for (int e = 0; e < 16; ++e) shbuf[row][c0 + e] = hacc[e];
    }
    __syncthreads();
    {   // ein = [h_t | h_attn] @ W_edge^T -> LDS fragments
        f32x4 ea[2];
        ea[0] = (f32x4){0.f, 0.f, 0.f, 0.f};
        ea[1] = (f32x4){0.f, 0.f, 0.f, 0.f};
        #pragma unroll
        for (int kc = 0; kc < 16; ++kc) {
            bf16x8 af;
            if (kc < 8) {
                af = *(const bf16x8*)(htf_p + ((size_t)rb16n * 8 + kc) * 512 + lo8);
            } else {
                int k0 = (kc - 8) * 32 + (l >> 4) * 8;
                #pragma unroll
                for (int e = 0; e < 8; ++e)
                    ((u16*)&af)[e] = f2bf(shbuf[l15][k0 + e]);
            }
            #pragma unroll
            for (int j2 = 0; j2 < 2; ++j2) {
                bf16x8 bf = *(const bf16x8*)(Wef + ((size_t)((wid * 2 + j2) * 16 + kc)) * 512 + lo8);
                ea[j2] = __builtin_amdgcn_mfma_f32_16x16x32_bf16(af, bf, ea[j2], 0, 0, 0);
            }
        }
        #pragma unroll
        for (int j2 = 0; j2 < 2; ++j2) {
            int cell = (wid * 2 + j2) * 16 + l15;
            #pragma unroll
            for (int r = 0; r < 4; ++r) {
                int row = (l >> 4) * 4 + r;
                float v = ea[j2][r] + b_edge[cell];
                v = v > 0.f ? v : 0.f;
                einL[(size_t)(cell >> 5) * 512 + (((cell >> 3) & 3) * 16 + row) * 8 + (cell & 7)] = f2bf(v);
            }
        }
    }
    __syncthreads();
    {   // node LSTM GEMM: wave wid owns jb16 in [wid*16, wid*16+16), K=512
        f32x4 na[16];
        #pragma unroll
        for (int jj = 0; jj < 16; ++jj) {
            float bv = bs_n[(wid * 16 + jj) * 16 + l15];
            na[jj] = (f32x4){bv, bv, bv, bv};
        }
        for (int kc = 0; kc < 16; ++kc) {
            bf16x8 af;
            if (kc < 4)      af = *(const bf16x8*)(ninf_t + ((size_t)rb16n * 4 + kc) * 512 + lo8);
            else if (kc < 8) af = *(const bf16x8*)(einL + (size_t)(kc - 4) * 512 + lo8);
            else             af = *(const bf16x8*)(hnf_p + ((size_t)rb16n * 8 + (kc - 8)) * 512 + lo8);
            #pragma unroll 4
            for (int jj = 0; jj < 16; ++jj) {
                bf16x8 bf = *(const bf16x8*)(Wf_n + (((size_t)(wid * 16 + jj)) * 16 + kc) * 512 + lo8);
                na[jj] = __builtin_amdgcn_mfma_f32_16x16x32_bf16(af, bf, na[jj], 0, 0, 0);
            }
        }
        const int rofs = (l >> 4) << 2;
        #pragma unroll
        for (int ch = 0; ch < 4; ++ch) {
            int cell = (wid * 4 + ch) * 16 + l15;
            int cpart = (cell >> 5) * 512 + ((cell >> 3) & 3) * 128 + (cell & 7);
            #pragma unroll
            for (int r = 0; r < 4; ++r) {
                int rlow = rofs + r;
                size_t doff = ((size_t)rb16n * 16 + rlow) * 256 + cell;
                float gi = na[ch * 4 + 0][r], gf = na[ch * 4 + 1][r];
                float gg = na[ch * 4 + 2][r], go = na[ch * 4 + 3][r];
                float c2 = sigm(gf) * c_n[doff] + sigm(gi) * ftanh(gg);
                float h2 = sigm(go) * ftanh(c2);
                c_n[doff] = c2;
                u16 hb = f2bf(h2);
                hist1[doff] = hb;
                hnf_c[(size_t)rb16n * 4096 + cpart + rlow * 8] = hb;
            }
        }
    }
}

// out[b,t,n,q] = hist[t+1] . W_out^T + b_out
__global__ __launch_bounds__(256) void out_kernel(
    const u16* __restrict__ hist1, const float* __restrict__ W_out,
    const float* __restrict__ b_out, float* __restrict__ out)
{
    const int lane = threadIdx.x & 63;
    const int grp = threadIdx.x >> 6;
    for (int ridx = blockIdx.x * 4 + grp; ridx < 32 * 768; ridx += gridDim.x * 4) {
        int t = ridx / 768, row = ridx % 768;
        int b = row / 12, n = row % 12;
        const u16* h = &hist1[(size_t)ridx * 256];
        float hv[4];
        #pragma unroll
        for (int i = 0; i < 4; ++i) hv[i] = bf2f(h[i * 64 + lane]);
        #pragma unroll
        for (int q = 0; q < 5; ++q) {
            float s = 0.f;
            #pragma unroll
            for (int i = 0; i < 4; ++i) s = fmaf(hv[i], W_out[q * 256 + i * 64 + lane], s);
            #pragma unroll
            for (int off = 32; off > 0; off >>= 1) s += __shfl_down(s, off, 64);
            if (lane == 0)
                out[(((size_t)b * T_ + t) * N_ + n) * 5 + q] = s + b_out[q];
        }
    }
}

extern "C" void kernel_launch(void* const* d_in, const int* in_sizes, int n_in,
                              void* d_out, int out_size, void* d_ws, size_t ws_size,
                              hipStream_t stream)
{
    const float* nodes = (const float*)d_in[0];
    const float* et    = (const float*)d_in[1];
    const float* es    = (const float*)d_in[2];
    const float* W_te = (const float*)d_in[3];  const float* b_te = (const float*)d_in[4];
    const float* te_Wih = (const float*)d_in[5]; const float* te_Whh = (const float*)d_in[6];
    const float* te_bih = (const float*)d_in[7]; const float* te_bhh = (const float*)d_in[8];
    const float* W_se = (const float*)d_in[9];  const float* b_se = (const float*)d_in[10];
    const float* se_Wih = (const float*)d_in[11]; const float* se_Whh = (const float*)d_in[12];
    const float* se_bih = (const float*)d_in[13]; const float* se_bhh = (const float*)d_in[14];
    const float* Wq = (const float*)d_in[15]; const float* bq = (const float*)d_in[16];
    const float* Wk = (const float*)d_in[17]; const float* bk = (const float*)d_in[18];
    const float* W_node = (const float*)d_in[19]; const float* b_node = (const float*)d_in[20];
    const float* W_edge = (const float*)d_in[21]; const float* b_edge = (const float*)d_in[22];
    const float* nr_Wih = (const float*)d_in[23]; const float* nr_Whh = (const float*)d_in[24];
    const float* nr_bih = (const float*)d_in[25]; const float* nr_bhh = (const float*)d_in[26];
    const float* W_out = (const float*)d_in[27]; const float* b_out = (const float*)d_in[28];

    char* base = (char*)d_ws;
    size_t off = 0;
    auto A = [&](size_t bytes) { char* p = base + off; off += (bytes + 255) & ~(size_t)255; return p; };

    // zero region: c-states (f32) + t=0 frag h-states (bf16), contiguous
    float* c_t = (float*)A(768 * 256 * 4);
    float* c_s = (float*)A((size_t)8448 * 256 * 4);
    float* c_n = (float*)A(768 * 256 * 4);
    u16* htf0 = (u16*)A(768 * 256 * 2);
    u16* hsf0 = (u16*)A((size_t)8448 * 256 * 2);
    u16* hnf0 = (u16*)A(768 * 256 * 2);
    size_t zero_bytes = off;
    u16* htf1 = (u16*)A(768 * 256 * 2);
    u16* hsf1 = (u16*)A((size_t)8448 * 256 * 2);
    u16* hnf1 = (u16*)A(768 * 256 * 2);
    u16* hs_d0 = (u16*)A((size_t)8448 * 256 * 2);
    u16* hs_d1 = (u16*)A((size_t)8448 * 256 * 2);
    u16* hist = (u16*)A((size_t)33 * 768 * 256 * 2);
    u16* tef  = (u16*)A((size_t)32 * 768 * 128 * 2);
    u16* ninf = (u16*)A((size_t)32 * 768 * 128 * 2);
    u16* Wf_t = (u16*)A(1024 * 384 * 2);
    u16* Wf_s = (u16*)A(1024 * 384 * 2);
    u16* Wf_n = (u16*)A(1024 * 512 * 2);
    float* bs_t = (float*)A(1024 * 4);
    float* bs_s = (float*)A(1024 * 4);
    float* bs_n = (float*)A(1024 * 4);
    u16* Wqf  = (u16*)A(2048 * 8 * 2);
    u16* Wkqf = (u16*)A(2048 * 8 * 2);
    u16* Wef  = (u16*)A(8192 * 8 * 2);

    const size_t sef_full_bytes = (size_t)32 * 8448 * 128 * 2;
    bool sef_full = (off + sef_full_bytes + 4096) <= ws_size;
    u16* sef = (u16*)A(sef_full ? sef_full_bytes : (size_t)8448 * 128 * 2);

    hipMemsetAsync(base, 0, zero_bytes, stream);

    prep_kernel<<<256, 256, 0, stream>>>(
        te_Wih, te_Whh, te_bih, te_bhh, se_Wih, se_Whh, se_bih, se_bhh,
        nr_Wih, nr_Whh, nr_bih, nr_bhh, Wq, Wk, W_edge,
        Wf_t, Wf_s, Wf_n, bs_t, bs_s, bs_n, Wqf, Wkqf, Wef);

    emb_tn_kernel<<<1536, 256, 0, stream>>>(et, nodes, W_te, b_te, W_node, b_node, tef, ninf);

    if (sef_full)
        emb_se_kernel<<<16896, 256, 0, stream>>>(0, es, W_se, b_se, sef);
    else
        emb_se_kernel<<<528, 256, 0, stream>>>(0, es, W_se, b_se, sef);

    u16* htf[2] = {htf0, htf1};
    u16* hsf[2] = {hsf0, hsf1};
    u16* hnf[2] = {hnf0, hnf1};
    u16* hsd[2] = {hs_d0, hs_d1};

    auto sef_ptr = [&](int t) {
        return sef_full ? sef + (size_t)t * 528 * 4 * 512 : sef;
    };

    // prologue: lstm(0) only. lstm(s): prev idx s&1, cur idx (s+1)&1, dense hsd[(s+1)&1]
    step_kernel<<<576, 256, 0, stream>>>(
        576, -1,
        sef_ptr(0), tef,
        Wf_t, bs_t, Wf_s, bs_s,
        htf[0], htf[1], c_t,
        hsf[0], hsf[1], hsd[1], c_s,
        hsd[0],
        ninf, Wf_n, bs_n, hnf[0], hnf[1], hist, c_n,
        Wqf, bq, Wkqf, bk, Wef, b_edge);

    // D(t): lstm(t+1) [if t<T-1] || node+attn(t)
    for (int t = 0; t < T_; ++t) {
        int nl = (t < T_ - 1) ? 576 : 0;
        if (!sef_full && t < T_ - 1)
            emb_se_kernel<<<528, 256, 0, stream>>>(t + 1, es, W_se, b_se, sef);
        int p2 = (t + 1) & 1;    // lstm(t+1) prev index; also = node's h(t) read index
        int tnext = (t + 1 < T_) ? (t + 1) : 0;
        step_kernel<<<nl + 48, 256, 0, stream>>>(
            nl, t,
            sef_ptr(tnext), tef + (size_t)tnext * 48 * 4 * 512,
            Wf_t, bs_t, Wf_s, bs_s,
            htf[p2], htf[p2 ^ 1], c_t,
            hsf[p2], hsf[p2 ^ 1], hsd[t & 1], c_s,
            hsd[p2],
            ninf + (size_t)t * 48 * 4 * 512, Wf_n, bs_n,
            hnf[t & 1], hnf[p2], hist + (size_t)(t + 1) * 768 * 256, c_n,
            Wqf, bq, Wkqf, bk, Wef, b_edge);
    }

    out_kernel<<<1536, 256, 0, stream>>>(hist + (size_t)768 * 256, W_out, b_out, (float*)d_out);
}

// Round 7
// 1732.506 us; speedup vs baseline: 1.9100x; 1.9100x over previous
//
#include <hip/hip_runtime.h>
#include <math.h>

#define B_ 64
#define T_ 32
#define N_ 12
#define NS_ 132
#define KN_ 11
#define TEMP_ 1.375f   // K_NEIGH / sqrt(ATTN) = 11/8

typedef unsigned short u16;
typedef __attribute__((ext_vector_type(8))) short bf16x8;
typedef __attribute__((ext_vector_type(8))) unsigned short u16x8;
typedef __attribute__((ext_vector_type(4))) float f32x4;

__device__ __forceinline__ float sigm(float x) { return 1.f / (1.f + __expf(-x)); }
__device__ __forceinline__ float ftanh(float x) {
    float a = fabsf(x);
    float e = __expf(-2.f * a);
    float t = (1.f - e) / (1.f + e);
    return copysignf(t, x);
}
__device__ __forceinline__ u16 f2bf(float x) {
    union { float f; unsigned u; } v; v.f = x;
    unsigned r = v.u + 0x7fffu + ((v.u >> 16) & 1u);
    return (u16)(r >> 16);
}
__device__ __forceinline__ float bf2f(u16 h) {
    union { unsigned u; float f; } v; v.u = ((unsigned)h) << 16; return v.f;
}
// reordered gate-space col j -> original gate col: j = cellhi*64 + gate*16 + celllo
__device__ __forceinline__ int origcol(int j) {
    return ((j >> 4) & 3) * 256 + ((j >> 6) << 4) + (j & 15);
}

// Fragment layout for M[R][K] (A/B operand of mfma 16x16x32 bf16):
//   tile = (r>>4)*(K/32) + (k>>5); lane = ((k>>3)&3)*16 + (r&15); elem = k&7
//   flat u16 index = tile*512 + lane*8 + elem

// ---------------------------------------------------------------------------
// prep: all weights -> bf16 fragment layout, fused biases.
// ---------------------------------------------------------------------------
__global__ __launch_bounds__(256) void prep_kernel(
    const float* __restrict__ te_Wih, const float* __restrict__ te_Whh,
    const float* __restrict__ te_bih, const float* __restrict__ te_bhh,
    const float* __restrict__ se_Wih, const float* __restrict__ se_Whh,
    const float* __restrict__ se_bih, const float* __restrict__ se_bhh,
    const float* __restrict__ nr_Wih, const float* __restrict__ nr_Whh,
    const float* __restrict__ nr_bih, const float* __restrict__ nr_bhh,
    const float* __restrict__ Wq, const float* __restrict__ Wk,
    const float* __restrict__ W_edge,
    u16* __restrict__ Wf_t, u16* __restrict__ Wf_s, u16* __restrict__ Wf_n,
    float* __restrict__ bs_t, float* __restrict__ bs_s, float* __restrict__ bs_n,
    u16* __restrict__ Wqf, u16* __restrict__ Wkqf, u16* __restrict__ Wef)
{
    int idx = blockIdx.x * 256 + threadIdx.x;
    if (idx < 49152) {                 // Wf_t / Wf_s: 64 jb16 x 12 kc x 64 lanes
        int l = idx & 63, kc = (idx >> 6) % 12, jb16 = idx / 768;
        int j = jb16 * 16 + (l & 15);
        int c = origcol(j);
        int k0 = kc * 32 + (l >> 4) * 8;
        u16x8 vt, vs;
        #pragma unroll
        for (int i = 0; i < 8; ++i) {
            int k = k0 + i;
            vt[i] = f2bf((k < 128) ? te_Wih[c * 128 + k] : te_Whh[c * 256 + (k - 128)]);
            vs[i] = f2bf((k < 128) ? se_Wih[c * 128 + k] : se_Whh[c * 256 + (k - 128)]);
        }
        *(u16x8*)(Wf_t + (size_t)idx * 8) = vt;
        *(u16x8*)(Wf_s + (size_t)idx * 8) = vs;
    }
    if (idx < 65536) {                 // Wf_n: 64 jb16 x 16 kc x 64 lanes
        int l = idx & 63, kc = (idx >> 6) & 15, jb16 = idx >> 10;
        int j = jb16 * 16 + (l & 15);
        int c = origcol(j);
        int k0 = kc * 32 + (l >> 4) * 8;
        u16x8 vn;
        #pragma unroll
        for (int i = 0; i < 8; ++i) {
            int k = k0 + i;
            vn[i] = f2bf((k < 256) ? nr_Wih[c * 256 + k] : nr_Whh[c * 256 + (k - 256)]);
        }
        *(u16x8*)(Wf_n + (size_t)idx * 8) = vn;
    }
    if (idx < 1024) {
        int c = origcol(idx);
        bs_t[idx] = te_bih[c] + te_bhh[c];
        bs_s[idx] = se_bih[c] + se_bhh[c];
        bs_n[idx] = nr_bih[c] + nr_bhh[c];
    }
    if (idx < 2048) {                  // Wqf: B[a][k], a<64, K=256 -> 4 jb x 8 kc
        int l = idx & 63, tile = idx >> 6;
        int a = (tile >> 3) * 16 + (l & 15);
        int k0 = (tile & 7) * 32 + (l >> 4) * 8;
        u16x8 v;
        #pragma unroll
        for (int i = 0; i < 8; ++i) v[i] = f2bf(Wq[a * 256 + k0 + i]);
        *(u16x8*)(Wqf + (size_t)idx * 8) = v;
    }
    if (idx < 2048) {                  // Wkqf: B[j][a] = Wk[a][j], j<256, K=64 -> 16 jb x 2 kc
        int l = idx & 63, tile = idx >> 6;
        int j = (tile >> 1) * 16 + (l & 15);
        int a0 = (tile & 1) * 32 + (l >> 4) * 8;
        u16x8 v;
        #pragma unroll
        for (int i = 0; i < 8; ++i) v[i] = f2bf(Wk[(a0 + i) * 256 + j]);
        *(u16x8*)(Wkqf + (size_t)idx * 8) = v;
    }
    if (idx < 8192) {                  // Wef: B[c][k], c<128, K=512 -> 8 jb x 16 kc
        int l = idx & 63, tile = idx >> 6;
        int c = (tile >> 4) * 16 + (l & 15);
        int k0 = (tile & 15) * 32 + (l >> 4) * 8;
        u16x8 v;
        #pragma unroll
        for (int i = 0; i < 8; ++i) v[i] = f2bf(W_edge[c * 512 + k0 + i]);
        *(u16x8*)(Wef + (size_t)idx * 8) = v;
    }
}

// te/nin embeddings in fragment layout: u = ((t*48+rb16)*4+kc)*64 + l
__global__ __launch_bounds__(256) void emb_tn_kernel(
    const float* __restrict__ et, const float* __restrict__ nodes,
    const float* __restrict__ W_te, const float* __restrict__ b_te,
    const float* __restrict__ W_node, const float* __restrict__ b_node,
    u16* __restrict__ tef, u16* __restrict__ ninf)
{
    int u = blockIdx.x * 256 + threadIdx.x;   // 32*48*4*64 = 393216 exact
    int l = u & 63, kc = (u >> 6) & 3;
    int rt = u >> 8;
    int rb16 = rt % 48, t = rt / 48;
    int row = rb16 * 16 + (l & 15);
    int b = row / 12, n = row - b * 12;
    size_t src = (((size_t)b * T_ + t) * N_ + n) * 2;
    float e0 = et[src], e1 = et[src + 1];
    float n0 = nodes[src], n1 = nodes[src + 1];
    int k0 = kc * 32 + (l >> 4) * 8;
    u16x8 vt, vn;
    #pragma unroll
    for (int i = 0; i < 8; ++i) {
        int k = k0 + i;
        float x = fmaf(e0, W_te[k * 2], fmaf(e1, W_te[k * 2 + 1], b_te[k]));
        vt[i] = f2bf(fmaxf(x, 0.f));
        float y = fmaf(n0, W_node[k * 2], fmaf(n1, W_node[k * 2 + 1], b_node[k]));
        vn[i] = f2bf(fmaxf(y, 0.f));
    }
    *(u16x8*)(tef + (size_t)u * 8) = vt;
    *(u16x8*)(ninf + (size_t)u * 8) = vn;
}

// spatial embeddings, fragment layout: u = ((trel*528+rb16)*4+kc)*64 + l
__global__ __launch_bounds__(256) void emb_se_kernel(
    int t0, const float* __restrict__ es,
    const float* __restrict__ W_se, const float* __restrict__ b_se,
    u16* __restrict__ sef)
{
    int u = blockIdx.x * 256 + threadIdx.x;
    int l = u & 63, kc = (u >> 6) & 3;
    int rt = u >> 8;
    int rb16 = rt % 528, trel = rt / 528;
    int row = rb16 * 16 + (l & 15);
    int b = row / NS_, s = row - b * NS_;
    size_t src = (((size_t)b * T_ + (t0 + trel)) * NS_ + s) * 2;
    float e0 = es[src], e1 = es[src + 1];
    int k0 = kc * 32 + (l >> 4) * 8;
    u16x8 v;
    #pragma unroll
    for (int i = 0; i < 8; ++i) {
        int k = k0 + i;
        float x = fmaf(e0, W_se[k * 2], fmaf(e1, W_se[k * 2 + 1], b_se[k]));
        v[i] = f2bf(fmaxf(x, 0.f));
    }
    *(u16x8*)(sef + (size_t)u * 8) = v;
}

// ---------------------------------------------------------------------------
// step_kernel: blocks [0,48) = attn + edge + node LSTM for step t_node
// (scheduled FIRST so they overlap the lstm wave);
// blocks [48, 48+nlstm) = temporal+spatial LSTM step t+1, M-tile 64.
// ---------------------------------------------------------------------------
__global__ __launch_bounds__(256) void step_kernel(
    int nlstm, int t_node,
    const u16* __restrict__ sef_step, const u16* __restrict__ tef_step,
    const u16* __restrict__ Wf_t, const float* __restrict__ bs_t,
    const u16* __restrict__ Wf_s, const float* __restrict__ bs_s,
    const u16* __restrict__ htf_p, u16* __restrict__ htf_c, float* __restrict__ c_t,
    const u16* __restrict__ hsf_p, u16* __restrict__ hsf_c,
    u16* __restrict__ hsd_w, float* __restrict__ c_s,
    const u16* __restrict__ hsd_r,
    const u16* __restrict__ ninf_t,
    const u16* __restrict__ Wf_n, const float* __restrict__ bs_n,
    const u16* __restrict__ hnf_p, u16* __restrict__ hnf_c,
    u16* __restrict__ hist1, float* __restrict__ c_n,
    const u16* __restrict__ Wqf, const float* __restrict__ bq,
    const u16* __restrict__ Wkqf, const float* __restrict__ bk,
    const u16* __restrict__ Wef, const float* __restrict__ b_edge)
{
    const int tid = threadIdx.x;
    const int l = tid & 63, l15 = l & 15;
    const size_t lo8 = (size_t)l * 8;

    if ((int)blockIdx.x >= 48) {
        // ================= temporal+spatial LSTM tile (M=64) =================
        const int lb = blockIdx.x - 48;
        const bool spatial = lb < 1056;
        int rb, jc;
        if (spatial) {
            int orig = (lb & 7) * 132 + (lb >> 3);   // XCD chunking (1056%8==0)
            rb = orig >> 3; jc = orig & 7;
        } else {
            int q = lb - 1056;
            rb = q >> 3; jc = q & 7;
        }
        const u16* Ef = spatial ? sef_step : tef_step;
        const u16* Hf = spatial ? hsf_p : htf_p;
        const u16* Wf = spatial ? Wf_s : Wf_t;
        const float* bs = spatial ? bs_s : bs_t;
        u16* Hfc = spatial ? hsf_c : htf_c;
        float* C  = spatial ? c_s : c_t;

        const int wid = tid >> 6;
        const int wm = wid >> 1, wn = wid & 1;
        const int rb16 = rb * 4 + wm * 2;    // + mf (0..1)
        const int jb16 = jc * 8 + wn * 4;    // + g

        f32x4 acc[2][4];
        #pragma unroll
        for (int g = 0; g < 4; ++g) {
            float bv = bs[jc * 128 + wn * 64 + g * 16 + l15];
            acc[0][g] = (f32x4){bv, bv, bv, bv};
            acc[1][g] = (f32x4){bv, bv, bv, bv};
        }

        auto loadA = [&](int kc, bf16x8* a) {
            #pragma unroll
            for (int mf = 0; mf < 2; ++mf) {
                const u16* p = (kc < 4)
                    ? Ef + (((size_t)(rb16 + mf)) * 4 + kc) * 512 + lo8
                    : Hf + (((size_t)(rb16 + mf)) * 8 + (kc - 4)) * 512 + lo8;
                a[mf] = *(const bf16x8*)p;
            }
        };
        auto loadB = [&](int kc, bf16x8* b) {
            #pragma unroll
            for (int g = 0; g < 4; ++g)
                b[g] = *(const bf16x8*)(Wf + (((size_t)(jb16 + g)) * 12 + kc) * 512 + lo8);
        };
        auto domfma = [&](bf16x8* a, bf16x8* b) {
            #pragma unroll
            for (int mf = 0; mf < 2; ++mf)
                #pragma unroll
                for (int g = 0; g < 4; ++g)
                    acc[mf][g] = __builtin_amdgcn_mfma_f32_16x16x32_bf16(a[mf], b[g], acc[mf][g], 0, 0, 0);
        };

        bf16x8 a0[2], b0[4], a1[2], b1[4];
        loadA(0, a0); loadB(0, b0);
        #pragma unroll
        for (int kc = 0; kc < 12; kc += 2) {
            loadA(kc + 1, a1); loadB(kc + 1, b1);
            domfma(a0, b0);
            if (kc + 2 < 12) { loadA(kc + 2, a0); loadB(kc + 2, b0); }
            domfma(a1, b1);
        }

        const int cell = (jc * 2 + wn) * 16 + l15;
        const int rofs = (l >> 4) << 2;
        const int cpart = (cell >> 5) * 512 + ((cell >> 3) & 3) * 128 + (cell & 7);
        #pragma unroll
        for (int mf = 0; mf < 2; ++mf) {
            int r16 = rb16 + mf;
            #pragma unroll
            for (int r = 0; r < 4; ++r) {
                int rlow = rofs + r;
                size_t doff = ((size_t)r16 * 16 + rlow) * 256 + cell;
                float gi = acc[mf][0][r], gf = acc[mf][1][r], gg = acc[mf][2][r], go = acc[mf][3][r];
                float c2 = sigm(gf) * C[doff] + sigm(gi) * ftanh(gg);
                float h2 = sigm(go) * ftanh(c2);
                C[doff] = c2;
                u16 hb = f2bf(h2);
                if (spatial) hsd_w[doff] = hb;
                Hfc[(size_t)r16 * 4096 + cpart + rlow * 8] = hb;
            }
        }
        return;
    }

    // ================= attn + edge + node LSTM (step t_node) =================
    if (t_node < 0) return;
    const int rb16n = blockIdx.x;           // 0..47
    const int wid = tid >> 6;

    __shared__ float q_lds[16][68];
    __shared__ float shbuf[16][260];        // qk, then (after 2 barriers) h_attn
    __shared__ float sc_lds[16][12];
    __shared__ float w_lds[16][12];
    __shared__ float qb_lds[16];
    __shared__ u16 einL[2048];              // ein fragments: 4 tiles x 512

    if (wid == 0) {   // q = h_t @ Wq^T : 4 jb x 8 kc
        f32x4 qa[4];
        #pragma unroll
        for (int jb = 0; jb < 4; ++jb) qa[jb] = (f32x4){0.f, 0.f, 0.f, 0.f};
        #pragma unroll
        for (int kc = 0; kc < 8; ++kc) {
            bf16x8 af = *(const bf16x8*)(htf_p + ((size_t)rb16n * 8 + kc) * 512 + lo8);
            #pragma unroll
            for (int jb = 0; jb < 4; ++jb) {
                bf16x8 bf = *(const bf16x8*)(Wqf + ((size_t)(jb * 8 + kc)) * 512 + lo8);
                qa[jb] = __builtin_amdgcn_mfma_f32_16x16x32_bf16(af, bf, qa[jb], 0, 0, 0);
            }
        }
        #pragma unroll
        for (int jb = 0; jb < 4; ++jb) {
            int a = jb * 16 + l15;
            #pragma unroll
            for (int r = 0; r < 4; ++r)
                q_lds[(l >> 4) * 4 + r][a] = qa[jb][r] + bq[a];
        }
    }
    __syncthreads();
    if (wid == 0) {   // qk = q @ Wk : 2 halves x 8 jb x 2 kc (K = 64)
        #pragma unroll
        for (int half = 0; half < 2; ++half) {
            f32x4 ka[8];
            #pragma unroll
            for (int jb = 0; jb < 8; ++jb) ka[jb] = (f32x4){0.f, 0.f, 0.f, 0.f};
            #pragma unroll
            for (int kc = 0; kc < 2; ++kc) {
                int a0 = kc * 32 + (l >> 4) * 8;
                bf16x8 af;
                #pragma unroll
                for (int e = 0; e < 8; ++e)
                    ((u16*)&af)[e] = f2bf(q_lds[l15][a0 + e]);
                #pragma unroll
                for (int jb = 0; jb < 8; ++jb) {
                    bf16x8 bf = *(const bf16x8*)(Wkqf + ((size_t)((half * 8 + jb) * 2 + kc)) * 512 + lo8);
                    ka[jb] = __builtin_amdgcn_mfma_f32_16x16x32_bf16(af, bf, ka[jb], 0, 0, 0);
                }
            }
            #pragma unroll
            for (int jb = 0; jb < 8; ++jb)
                #pragma unroll
                for (int r = 0; r < 4; ++r)
                    shbuf[(l >> 4) * 4 + r][(half * 8 + jb) * 16 + l15] = ka[jb][r];
        }
    }
    if (wid == 1 && l < 16) {   // qb[row] = q_full . bk
        float s = 0.f;
        for (int a = 0; a < 64; ++a) s = fmaf(q_lds[l][a], bk[a], s);
        qb_lds[l] = s;
    }
    __syncthreads();
    if (tid < 176) {   // scores: (row, kk), qk in shbuf
        int row = tid / 11, kk = tid - row * 11;
        int r = rb16n * 16 + row;
        int srow = (r / 12) * 132 + (r % 12) * 11 + kk;
        const u16* hp = hsd_r + (size_t)srow * 256;
        float s = 0.f;
        for (int k = 0; k < 256; k += 8) {
            u16x8 v = *(const u16x8*)(hp + k);
            #pragma unroll
            for (int e = 0; e < 8; ++e) s = fmaf(shbuf[row][k + e], bf2f(v[e]), s);
        }
        sc_lds[row][kk] = (s + qb_lds[row]) * TEMP_;
    }
    __syncthreads();
    if (tid < 16) {   // softmax over 11
        float m = sc_lds[tid][0];
        #pragma unroll
        for (int kk = 1; kk < 11; ++kk) m = fmaxf(m, sc_lds[tid][kk]);
        float ssum = 0.f;
        float wv[11];
        #pragma unroll
        for (int kk = 0; kk < 11; ++kk) { wv[kk] = __expf(sc_lds[tid][kk] - m); ssum += wv[kk]; }
        float inv = 1.f / ssum;
        #pragma unroll
        for (int kk = 0; kk < 11; ++kk) w_lds[tid][kk] = wv[kk] * inv;
    }
    __syncthreads();
    {   // h_attn -> shbuf (qk dead now): thread = (row, 16-col chunk)
        int row = tid >> 4, c0 = (tid & 15) * 16;
        int r = rb16n * 16 + row;
        int sbase = (r / 12) * 132 + (r % 12) * 11;
        float hacc[16];
        #pragma unroll
        for (int e = 0; e < 16; ++e) hacc[e] = 0.f;
        #pragma unroll
        for (int kk = 0; kk < 11; ++kk) {
            float wv = w_lds[row][kk];
            const u16* hp = hsd_r + (size_t)(sbase + kk) * 256 + c0;
            u16x8 v0 = *(const u16x8*)hp;
            u16x8 v1 = *(const u16x8*)(hp + 8);
            #pragma unroll
            for (int e = 0; e < 8; ++e) {
                hacc[e]     = fmaf(wv, bf2f(v0[e]), hacc[e]);
                hacc[8 + e] = fmaf(wv, bf2f(v1[e]), hacc[8 + e]);
            }
        }
        #pragma unroll
        for (int e = 0; e < 16; ++e) shbuf[row][c0 + e] = hacc[e];
    }
    __syncthreads();
    {   // ein = [h_t | h_attn] @ W_edge^T -> LDS fragments
        f32x4 ea[2];
        ea[0] = (f32x4){0.f, 0.f, 0.f, 0.f};
        ea[1] = (f32x4){0.f, 0.f, 0.f, 0.f};
        #pragma unroll
        for (int kc = 0; kc < 16; ++kc) {
            bf16x8 af;
            if (kc < 8) {
                af = *(const bf16x8*)(htf_p + ((size_t)rb16n * 8 + kc) * 512 + lo8);
            } else {
                int k0 = (kc - 8) * 32 + (l >> 4) * 8;
                #pragma unroll
                for (int e = 0; e < 8; ++e)
                    ((u16*)&af)[e] = f2bf(shbuf[l15][k0 + e]);
            }
            #pragma unroll
            for (int j2 = 0; j2 < 2; ++j2) {
                bf16x8 bf = *(const bf16x8*)(Wef + ((size_t)((wid * 2 + j2) * 16 + kc)) * 512 + lo8);
                ea[j2] = __builtin_amdgcn_mfma_f32_16x16x32_bf16(af, bf, ea[j2], 0, 0, 0);
            }
        }
        #pragma unroll
        for (int j2 = 0; j2 < 2; ++j2) {
            int cell = (wid * 2 + j2) * 16 + l15;
            #pragma unroll
            for (int r = 0; r < 4; ++r) {
                int row = (l >> 4) * 4 + r;
                float v = ea[j2][r] + b_edge[cell];
                v = v > 0.f ? v : 0.f;
                einL[(size_t)(cell >> 5) * 512 + (((cell >> 3) & 3) * 16 + row) * 8 + (cell & 7)] = f2bf(v);
            }
        }
    }
    __syncthreads();
    {   // node LSTM GEMM: wave wid owns jb16 [wid*16, wid*16+16), K=512.
        // ALL accumulator indices compile-time (rule #20: no partial unrolls).
        f32x4 na[4][4];   // [ch][gate]
        #pragma unroll
        for (int ch = 0; ch < 4; ++ch)
            #pragma unroll
            for (int g = 0; g < 4; ++g) {
                float bv = bs_n[(wid * 16 + ch * 4 + g) * 16 + l15];
                na[ch][g] = (f32x4){bv, bv, bv, bv};
            }
        for (int kc = 0; kc < 16; ++kc) {
            bf16x8 af;
            if (kc < 4)      af = *(const bf16x8*)(ninf_t + ((size_t)rb16n * 4 + kc) * 512 + lo8);
            else if (kc < 8) af = *(const bf16x8*)(einL + (size_t)(kc - 4) * 512 + lo8);
            else             af = *(const bf16x8*)(hnf_p + ((size_t)rb16n * 8 + (kc - 8)) * 512 + lo8);
            const u16* wb = Wf_n + (((size_t)(wid * 16)) * 16 + kc) * 512 + lo8;
            #pragma unroll
            for (int ch = 0; ch < 4; ++ch)
                #pragma unroll
                for (int g = 0; g < 4; ++g) {
                    bf16x8 bf = *(const bf16x8*)(wb + (size_t)(ch * 4 + g) * 16 * 512);
                    na[ch][g] = __builtin_amdgcn_mfma_f32_16x16x32_bf16(af, bf, na[ch][g], 0, 0, 0);
                }
        }
        const int rofs = (l >> 4) << 2;
        #pragma unroll
        for (int ch = 0; ch < 4; ++ch) {
            int cell = (wid * 4 + ch) * 16 + l15;
            int cpart = (cell >> 5) * 512 + ((cell >> 3) & 3) * 128 + (cell & 7);
            #pragma unroll
            for (int r = 0; r < 4; ++r) {
                int rlow = rofs + r;
                size_t doff = ((size_t)rb16n * 16 + rlow) * 256 + cell;
                float gi = na[ch][0][r], gf = na[ch][1][r];
                float gg = na[ch][2][r], go = na[ch][3][r];
                float c2 = sigm(gf) * c_n[doff] + sigm(gi) * ftanh(gg);
                float h2 = sigm(go) * ftanh(c2);
                c_n[doff] = c2;
                u16 hb = f2bf(h2);
                hist1[doff] = hb;
                hnf_c[(size_t)rb16n * 4096 + cpart + rlow * 8] = hb;
            }
        }
    }
}

// out[b,t,n,q] = hist[t+1] . W_out^T + b_out
__global__ __launch_bounds__(256) void out_kernel(
    const u16* __restrict__ hist1, const float* __restrict__ W_out,
    const float* __restrict__ b_out, float* __restrict__ out)
{
    const int lane = threadIdx.x & 63;
    const int grp = threadIdx.x >> 6;
    for (int ridx = blockIdx.x * 4 + grp; ridx < 32 * 768; ridx += gridDim.x * 4) {
        int t = ridx / 768, row = ridx % 768;
        int b = row / 12, n = row % 12;
        const u16* h = &hist1[(size_t)ridx * 256];
        float hv[4];
        #pragma unroll
        for (int i = 0; i < 4; ++i) hv[i] = bf2f(h[i * 64 + lane]);
        #pragma unroll
        for (int q = 0; q < 5; ++q) {
            float s = 0.f;
            #pragma unroll
            for (int i = 0; i < 4; ++i) s = fmaf(hv[i], W_out[q * 256 + i * 64 + lane], s);
            #pragma unroll
            for (int off = 32; off > 0; off >>= 1) s += __shfl_down(s, off, 64);
            if (lane == 0)
                out[(((size_t)b * T_ + t) * N_ + n) * 5 + q] = s + b_out[q];
        }
    }
}

extern "C" void kernel_launch(void* const* d_in, const int* in_sizes, int n_in,
                              void* d_out, int out_size, void* d_ws, size_t ws_size,
                              hipStream_t stream)
{
    const float* nodes = (const float*)d_in[0];
    const float* et    = (const float*)d_in[1];
    const float* es    = (const float*)d_in[2];
    const float* W_te = (const float*)d_in[3];  const float* b_te = (const float*)d_in[4];
    const float* te_Wih = (const float*)d_in[5]; const float* te_Whh = (const float*)d_in[6];
    const float* te_bih = (const float*)d_in[7]; const float* te_bhh = (const float*)d_in[8];
    const float* W_se = (const float*)d_in[9];  const float* b_se = (const float*)d_in[10];
    const float* se_Wih = (const float*)d_in[11]; const float* se_Whh = (const float*)d_in[12];
    const float* se_bih = (const float*)d_in[13]; const float* se_bhh = (const float*)d_in[14];
    const float* Wq = (const float*)d_in[15]; const float* bq = (const float*)d_in[16];
    const float* Wk = (const float*)d_in[17]; const float* bk = (const float*)d_in[18];
    const float* W_node = (const float*)d_in[19]; const float* b_node = (const float*)d_in[20];
    const float* W_edge = (const float*)d_in[21]; const float* b_edge = (const float*)d_in[22];
    const float* nr_Wih = (const float*)d_in[23]; const float* nr_Whh = (const float*)d_in[24];
    const float* nr_bih = (const float*)d_in[25]; const float* nr_bhh = (const float*)d_in[26];
    const float* W_out = (const float*)d_in[27]; const float* b_out = (const float*)d_in[28];

    char* base = (char*)d_ws;
    size_t off = 0;
    auto A = [&](size_t bytes) { char* p = base + off; off += (bytes + 255) & ~(size_t)255; return p; };

    // zero region: c-states (f32) + t=0 frag h-states (bf16), contiguous
    float* c_t = (float*)A(768 * 256 * 4);
    float* c_s = (float*)A((size_t)8448 * 256 * 4);
    float* c_n = (float*)A(768 * 256 * 4);
    u16* htf0 = (u16*)A(768 * 256 * 2);
    u16* hsf0 = (u16*)A((size_t)8448 * 256 * 2);
    u16* hnf0 = (u16*)A(768 * 256 * 2);
    size_t zero_bytes = off;
    u16* htf1 = (u16*)A(768 * 256 * 2);
    u16* hsf1 = (u16*)A((size_t)8448 * 256 * 2);
    u16* hnf1 = (u16*)A(768 * 256 * 2);
    u16* hs_d0 = (u16*)A((size_t)8448 * 256 * 2);
    u16* hs_d1 = (u16*)A((size_t)8448 * 256 * 2);
    u16* hist = (u16*)A((size_t)33 * 768 * 256 * 2);
    u16* tef  = (u16*)A((size_t)32 * 768 * 128 * 2);
    u16* ninf = (u16*)A((size_t)32 * 768 * 128 * 2);
    u16* Wf_t = (u16*)A(1024 * 384 * 2);
    u16* Wf_s = (u16*)A(1024 * 384 * 2);
    u16* Wf_n = (u16*)A(1024 * 512 * 2);
    float* bs_t = (float*)A(1024 * 4);
    float* bs_s = (float*)A(1024 * 4);
    float* bs_n = (float*)A(1024 * 4);
    u16* Wqf  = (u16*)A(2048 * 8 * 2);
    u16* Wkqf = (u16*)A(2048 * 8 * 2);
    u16* Wef  = (u16*)A(8192 * 8 * 2);

    const size_t sef_full_bytes = (size_t)32 * 8448 * 128 * 2;
    bool sef_full = (off + sef_full_bytes + 4096) <= ws_size;
    u16* sef = (u16*)A(sef_full ? sef_full_bytes : (size_t)8448 * 128 * 2);

    hipMemsetAsync(base, 0, zero_bytes, stream);

    prep_kernel<<<256, 256, 0, stream>>>(
        te_Wih, te_Whh, te_bih, te_bhh, se_Wih, se_Whh, se_bih, se_bhh,
        nr_Wih, nr_Whh, nr_bih, nr_bhh, Wq, Wk, W_edge,
        Wf_t, Wf_s, Wf_n, bs_t, bs_s, bs_n, Wqf, Wkqf, Wef);

    emb_tn_kernel<<<1536, 256, 0, stream>>>(et, nodes, W_te, b_te, W_node, b_node, tef, ninf);

    if (sef_full)
        emb_se_kernel<<<16896, 256, 0, stream>>>(0, es, W_se, b_se, sef);
    else
        emb_se_kernel<<<528, 256, 0, stream>>>(0, es, W_se, b_se, sef);

    u16* htf[2] = {htf0, htf1};
    u16* hsf[2] = {hsf0, hsf1};
    u16* hnf[2] = {hnf0, hnf1};
    u16* hsd[2] = {hs_d0, hs_d1};

    auto sef_ptr = [&](int t) {
        return sef_full ? sef + (size_t)t * 528 * 4 * 512 : sef;
    };

    const int NLSTM = 1152;   // 1056 spatial + 96 temporal (M-tile 64)

    // prologue: lstm(0) only (node blocks no-op via t_node=-1)
    step_kernel<<<48 + NLSTM, 256, 0, stream>>>(
        NLSTM, -1,
        sef_ptr(0), tef,
        Wf_t, bs_t, Wf_s, bs_s,
        htf[0], htf[1], c_t,
        hsf[0], hsf[1], hsd[1], c_s,
        hsd[0],
        ninf, Wf_n, bs_n, hnf[0], hnf[1], hist, c_n,
        Wqf, bq, Wkqf, bk, Wef, b_edge);

    // D(t): node+attn(t) [blocks 0..47] || lstm(t+1) [if t<T-1]
    for (int t = 0; t < T_; ++t) {
        int nl = (t < T_ - 1) ? NLSTM : 0;
        if (!sef_full && t < T_ - 1)
            emb_se_kernel<<<528, 256, 0, stream>>>(t + 1, es, W_se, b_se, sef);
        int p2 = (t + 1) & 1;    // lstm(t+1) prev index; also node's h(t) read index
        int tnext = (t + 1 < T_) ? (t + 1) : 0;
        step_kernel<<<48 + nl, 256, 0, stream>>>(
            nl, t,
            sef_ptr(tnext), tef + (size_t)tnext * 48 * 4 * 512,
            Wf_t, bs_t, Wf_s, bs_s,
            htf[p2], htf[p2 ^ 1], c_t,
            hsf[p2], hsf[p2 ^ 1], hsd[t & 1], c_s,
            hsd[p2],
            ninf + (size_t)t * 48 * 4 * 512, Wf_n, bs_n,
            hnf[t & 1], hnf[p2], hist + (size_t)(t + 1) * 768 * 256, c_n,
            Wqf, bq, Wkqf, bk, Wef, b_edge);
    }

    out_kernel<<<1536, 256, 0, stream>>>(hist + (size_t)768 * 256, W_out, b_out, (float*)d_out);
}